// Round 12
// baseline (417.196 us; speedup 1.0000x reference)
//
#include <hip/hip_runtime.h>
#include <hip/hip_bf16.h>
#include <math.h>

#define N_NODES 100000
#define EMB 128
#define N_EDGES 1600000
#define N_LAYERS 3

#define NB 400        // buckets
#define NPB 250       // nodes per bucket
#define CAP 8192      // pairs capacity per bucket (mean 4000, sigma 63)
#define CAPB 6144     // LDS stage capacity (fallback path if exceeded)
#define BSTR 16       // bcur padding stride (64B apart -> parallel L2 atomics)
#define EPT 8
#define BUCKET_THREADS 512
#define BUCKET_BLOCKS ((N_EDGES + BUCKET_THREADS * EPT - 1) / (BUCKET_THREADS * EPT))  // 391

typedef __bf16 bf16x8 __attribute__((ext_vector_type(8)));
typedef float f32x4 __attribute__((ext_vector_type(4)));

// ---------------- CSR build (unchanged: ~25us total) ----------------

__global__ __launch_bounds__(BUCKET_THREADS) void bucket_kernel(
    const int* __restrict__ src, const int* __restrict__ dst,
    int* __restrict__ bcur, unsigned* __restrict__ pairs) {
  __shared__ int scnt[NB];
  __shared__ int sbase[NB];
  const int t = threadIdx.x;
  if (t < NB) scnt[t] = 0;
  __syncthreads();
  unsigned pk[EPT];
  int bk[EPT], lofs[EPT];
  const int base_e = blockIdx.x * BUCKET_THREADS * EPT;
#pragma unroll
  for (int it = 0; it < EPT; ++it) {
    int i = base_e + it * BUCKET_THREADS + t;
    bk[it] = -1;
    if (i < N_EDGES) {
      int d = dst[i];
      int s = src[i];
      int b = d / NPB;
      int vloc = d - b * NPB;
      bk[it] = b;
      pk[it] = ((unsigned)vloc << 17) | (unsigned)s;
      lofs[it] = atomicAdd(&scnt[b], 1);
    }
  }
  __syncthreads();
  if (t < NB) sbase[t] = atomicAdd(&bcur[t * BSTR], scnt[t]);
  __syncthreads();
#pragma unroll
  for (int it = 0; it < EPT; ++it) {
    if (bk[it] >= 0) {
      int idx = sbase[bk[it]] + lofs[it];
      if (idx < CAP) pairs[(size_t)bk[it] * CAP + idx] = pk[it];
    }
  }
}

__device__ __forceinline__ int* scan512(int* pin, int* pout, int t) {
  for (int off = 1; off < 512; off <<= 1) {
    for (int i = t; i < 512; i += 256) {
      int v = pin[i];
      if (i >= off) v += pin[i - off];
      pout[i] = v;
    }
    __syncthreads();
    int* tmp = pin; pin = pout; pout = tmp;
  }
  return pin;
}

__global__ __launch_bounds__(256) void fillb_kernel(const unsigned* __restrict__ pairs,
                                                    const int* __restrict__ bcur,
                                                    int* __restrict__ row_ptr,
                                                    int* __restrict__ col) {
  __shared__ int sA[512], sB[512];
  __shared__ int cnt[NPB], cur[NPB];
  __shared__ unsigned pstage[CAPB];
  __shared__ int colstage[CAPB];
  const int t = threadIdx.x;
  const int b = blockIdx.x;

  for (int i = t; i < 512; i += 256) sA[i] = (i < NB) ? bcur[i * BSTR] : 0;
  __syncthreads();
  int* r = scan512(sA, sB, t);
  int base_b = b ? r[b - 1] : 0;
  int n = r[b] - base_b;
  if (n > CAP) n = CAP;
  const unsigned* pg = pairs + (size_t)b * CAP;
  const bool fits = (n <= CAPB);

  if (fits) for (int i = t; i < n; i += 256) pstage[i] = pg[i];
  if (t < NPB) cnt[t] = 0;
  __syncthreads();
  for (int i = t; i < n; i += 256) atomicAdd(&cnt[(fits ? pstage[i] : pg[i]) >> 17], 1);
  __syncthreads();
  for (int i = t; i < 512; i += 256) sA[i] = (i < NPB) ? cnt[i] : 0;
  __syncthreads();
  r = scan512(sA, sB, t);
  if (t < NPB) {
    int ex = r[t] - cnt[t];
    row_ptr[b * NPB + t] = base_b + ex;
    cur[t] = ex;
  }
  if (b == NB - 1 && t == 0) row_ptr[N_NODES] = N_EDGES;
  __syncthreads();
  for (int i = t; i < n; i += 256) {
    unsigned p = fits ? pstage[i] : pg[i];
    int pos = atomicAdd(&cur[p >> 17], 1);
    int s = (int)(p & 0x1FFFFu);
    if (fits) colstage[pos] = s;
    else col[base_b + pos] = s;
  }
  __syncthreads();
  if (fits) for (int i = t; i < n; i += 256) col[base_b + i] = colstage[i];
}

// ---------------- precompute ----------------

__global__ __launch_bounds__(256) void tobf16_kernel(const float* __restrict__ in,
                                                     __hip_bfloat16* __restrict__ xb) {
  size_t i = (size_t)blockIdx.x * 256 + threadIdx.x;  // 1.6M threads exactly
  const float4* p = (const float4*)in + i * 2;
  float4 a = p[0], b = p[1];
  union { __hip_bfloat16 h[8]; uint4 u; } r;
  r.h[0] = __float2bfloat16(a.x); r.h[1] = __float2bfloat16(a.y);
  r.h[2] = __float2bfloat16(a.z); r.h[3] = __float2bfloat16(a.w);
  r.h[4] = __float2bfloat16(b.x); r.h[5] = __float2bfloat16(b.y);
  r.h[6] = __float2bfloat16(b.z); r.h[7] = __float2bfloat16(b.w);
  ((uint4*)xb)[i] = r.u;
}

__global__ __launch_bounds__(256) void wt_kernel(const float* __restrict__ W,
                                                 __hip_bfloat16* __restrict__ WT) {
  int l = blockIdx.x;
  const float* Wl = W + (size_t)l * EMB * EMB;
  __hip_bfloat16* WTl = WT + (size_t)l * EMB * EMB;
  for (int i = threadIdx.x; i < EMB * EMB; i += 256) {
    int k = i >> 7, c = i & 127;
    WTl[c * EMB + k] = __float2bfloat16(Wl[i]);
  }
}

// ---------------- per-layer: standalone aggregate, then streaming GEMM ----

__device__ __forceinline__ float bf_lo(unsigned int w) { return __uint_as_float(w << 16); }
__device__ __forceinline__ float bf_hi(unsigned int w) { return __uint_as_float(w & 0xFFFF0000u); }

__device__ __forceinline__ float gelu_exact(float v) {
  return 0.5f * v * (1.f + erff(v * 0.70710678118654752f));
}

// 1 node per wave, NO block barrier (waves retire independently -> CU refills;
// R11 showed the fused barrier costs max(deg)/mean(deg) ~ 1.6x of gather time).
// uint4 quarter-wave gather: 4 edges per load instruction, 16 in flight.
__global__ __launch_bounds__(256, 8) void aggregate_kernel(
    const __hip_bfloat16* __restrict__ xb_in,
    const int* __restrict__ row_ptr,
    const int* __restrict__ col,
    const float* __restrict__ deg_inv,
    __hip_bfloat16* __restrict__ mb) {
  const int t = threadIdx.x;
  const int lane = t & 63;
  const int q = lane >> 4;
  const int l15 = lane & 15;
  const int v = __builtin_amdgcn_readfirstlane((blockIdx.x * 256 + t) >> 6);
  if (v >= N_NODES) return;

  const char* gbase = (const char*)xb_in + l15 * 16;  // 8 bf16 per lane
  const int beg = row_ptr[v], end = row_ptr[v + 1];
  float a0 = 0.f, a1 = 0.f, a2 = 0.f, a3 = 0.f, a4 = 0.f, a5 = 0.f, a6 = 0.f, a7 = 0.f;
#define ACC8(W) { a0 += bf_lo(W.x); a1 += bf_hi(W.x); a2 += bf_lo(W.y); a3 += bf_hi(W.y); \
                  a4 += bf_lo(W.z); a5 += bf_hi(W.z); a6 += bf_lo(W.w); a7 += bf_hi(W.w); }
  int e = beg;
  for (; e + 16 <= end; e += 16) {
    int u0 = col[e + q];
    int u1 = col[e + 4 + q];
    int u2 = col[e + 8 + q];
    int u3 = col[e + 12 + q];
    uint4 w0 = *(const uint4*)(gbase + (size_t)u0 * 256);
    uint4 w1 = *(const uint4*)(gbase + (size_t)u1 * 256);
    uint4 w2 = *(const uint4*)(gbase + (size_t)u2 * 256);
    uint4 w3 = *(const uint4*)(gbase + (size_t)u3 * 256);
    ACC8(w0) ACC8(w1) ACC8(w2) ACC8(w3)
  }
  for (; e < end; e += 4) {
    int idx = e + q;
    bool valid = idx < end;
    int u = col[valid ? idx : beg];
    uint4 w0 = *(const uint4*)(gbase + (size_t)u * 256);
    if (valid) ACC8(w0)
  }
#undef ACC8
  a0 += __shfl_xor(a0, 16, 64); a0 += __shfl_xor(a0, 32, 64);
  a1 += __shfl_xor(a1, 16, 64); a1 += __shfl_xor(a1, 32, 64);
  a2 += __shfl_xor(a2, 16, 64); a2 += __shfl_xor(a2, 32, 64);
  a3 += __shfl_xor(a3, 16, 64); a3 += __shfl_xor(a3, 32, 64);
  a4 += __shfl_xor(a4, 16, 64); a4 += __shfl_xor(a4, 32, 64);
  a5 += __shfl_xor(a5, 16, 64); a5 += __shfl_xor(a5, 32, 64);
  a6 += __shfl_xor(a6, 16, 64); a6 += __shfl_xor(a6, 32, 64);
  a7 += __shfl_xor(a7, 16, 64); a7 += __shfl_xor(a7, 32, 64);
  if (q == 0) {
    float di = deg_inv[v];
    union { __hip_bfloat16 h[8]; uint4 u4; } r;
    r.h[0] = __float2bfloat16(a0 * di); r.h[1] = __float2bfloat16(a1 * di);
    r.h[2] = __float2bfloat16(a2 * di); r.h[3] = __float2bfloat16(a3 * di);
    r.h[4] = __float2bfloat16(a4 * di); r.h[5] = __float2bfloat16(a5 * di);
    r.h[6] = __float2bfloat16(a6 * di); r.h[7] = __float2bfloat16(a7 * di);
    *(uint4*)((char*)mb + (size_t)v * 256 + l15 * 16) = r.u4;
  }
}

// Streaming GEMM: block 1024 thr / 16 rows (6250 blocks).
// Waves 0..7: one 16x16x128 MFMA tile each, A-frags direct from global mb,
// gelu staged bf16 in sM. All waves then flush one full row coalesced (256B)
// with bf16 residual add; LAST folds LayerNorm. Write amp 1.
template <int LAST>
__global__ __launch_bounds__(1024, 8) void gemm_kernel(
    const __hip_bfloat16* __restrict__ mb,
    const __hip_bfloat16* __restrict__ xb_in,
    const __hip_bfloat16* __restrict__ WTl,
    const float* __restrict__ bias,
    __hip_bfloat16* __restrict__ xb_out,
    float* __restrict__ xf_out,
    const float* __restrict__ gamma,
    const float* __restrict__ beta) {
  __shared__ __hip_bfloat16 sM[16][136];

  const int t = threadIdx.x;
  const int w = t >> 6;         // wave 0..15
  const int lane = t & 63;
  const int q = lane >> 4;      // k-group
  const int l15 = lane & 15;    // A-row
  const int row0b = blockIdx.x * 16;

  if (w < 8) {
    // B fragments: wave w -> col tile w
    bf16x8 bfr[4];
    const __hip_bfloat16* wp = WTl + (size_t)(w * 16 + l15) * EMB + q * 8;
#pragma unroll
    for (int ks = 0; ks < 4; ++ks)
      bfr[ks] = *(const bf16x8*)(wp + ks * 32);

    // A fragments direct from global mb; MFMA
    const __hip_bfloat16* ap = mb + (size_t)(row0b + l15) * EMB + q * 8;
    f32x4 acc = (f32x4)(0.f);
#pragma unroll
    for (int ks = 0; ks < 4; ++ks) {
      bf16x8 af = *(const bf16x8*)(ap + ks * 32);
      acc = __builtin_amdgcn_mfma_f32_16x16x32_bf16(af, bfr[ks], acc, 0, 0, 0);
    }
    const int colg = w * 16 + l15;
    const float bb = bias[colg];
#pragma unroll
    for (int j = 0; j < 4; ++j)
      sM[q * 4 + j][colg] = __float2bfloat16(gelu_exact(acc[j] + bb));
  }
  __syncthreads();

  // coalesced row flush: wave w -> row w; lane -> elems 2l, 2l+1
  {
    const size_t rowoff = (size_t)(row0b + w) * EMB;
    unsigned rg = *(const unsigned*)(&sM[w][lane * 2]);
    unsigned rr = *(const unsigned*)((const char*)xb_in + (rowoff + lane * 2) * 2);
    float v1 = bf_lo(rr) + bf_lo(rg);
    float v2 = bf_hi(rr) + bf_hi(rg);
    if (!LAST) {
      union { __hip_bfloat16 h[2]; unsigned u; } o;
      o.h[0] = __float2bfloat16(v1);
      o.h[1] = __float2bfloat16(v2);
      *(unsigned*)((char*)xb_out + (rowoff + lane * 2) * 2) = o.u;
    } else {
      float s = v1 + v2;
      float sq = fmaf(v1, v1, v2 * v2);
      for (int off = 1; off < 64; off <<= 1) {
        s += __shfl_xor(s, off, 64);
        sq += __shfl_xor(sq, off, 64);
      }
      float mu = s * (1.f / EMB);
      float var = sq * (1.f / EMB) - mu * mu;
      float rstd = rsqrtf(var + 1e-5f);
      float2 g = *(const float2*)(gamma + lane * 2);
      float2 be = *(const float2*)(beta + lane * 2);
      float2 o;
      o.x = (v1 - mu) * rstd * g.x + be.x;
      o.y = (v2 - mu) * rstd * g.y + be.y;
      *(float2*)(xf_out + rowoff + lane * 2) = o;
    }
  }
}

// ---------------- launch ----------------

extern "C" void kernel_launch(void* const* d_in, const int* in_sizes, int n_in,
                              void* d_out, int out_size, void* d_ws, size_t ws_size,
                              hipStream_t stream) {
  const int* edge_index = (const int*)d_in[0];
  const float* deg_inv = (const float*)d_in[1];
  const float* node_emb = (const float*)d_in[2];
  const float* W = (const float*)d_in[3];
  const float* b = (const float*)d_in[4];
  const float* gamma = (const float*)d_in[5];
  const float* beta = (const float*)d_in[6];
  const int* src = edge_index;
  const int* dst = edge_index + N_EDGES;
  float* x = (float*)d_out;  // fp32 output written once, post-LN

  char* ws = (char*)d_ws;
  auto take = [&](size_t bytes) {
    char* p = ws;
    ws += (bytes + 255) & ~(size_t)255;
    return p;
  };
  __hip_bfloat16* xbA = (__hip_bfloat16*)take((size_t)N_NODES * EMB * 2);  // bf16 stream ping
  __hip_bfloat16* xbB = (__hip_bfloat16*)take((size_t)N_NODES * EMB * 2);  // bf16 stream pong
  __hip_bfloat16* mb = (__hip_bfloat16*)take((size_t)N_NODES * EMB * 2);   // bf16 aggregate
  __hip_bfloat16* WT = (__hip_bfloat16*)take((size_t)N_LAYERS * EMB * EMB * 2);
  int* row_ptr = (int*)take((N_NODES + 1) * sizeof(int));
  int* col = (int*)take(N_EDGES * sizeof(int));
  int* bcur = (int*)take(NB * BSTR * sizeof(int));
  unsigned* pairs = (unsigned*)mb;  // alias: consumed by fillb before layer-0 aggregate

  hipMemsetAsync(bcur, 0, NB * BSTR * sizeof(int), stream);

  tobf16_kernel<<<N_NODES * EMB / 8 / 256, 256, 0, stream>>>(node_emb, xbA);
  wt_kernel<<<N_LAYERS, 256, 0, stream>>>(W, WT);

  bucket_kernel<<<BUCKET_BLOCKS, BUCKET_THREADS, 0, stream>>>(src, dst, bcur, pairs);
  fillb_kernel<<<NB, 256, 0, stream>>>(pairs, bcur, row_ptr, col);

  const int AGG_BLOCKS = (N_NODES + 3) / 4;   // 1 node/wave, 4 waves/block
  const int GEMM_BLOCKS = N_NODES / 16;       // 6250, exact

  aggregate_kernel<<<AGG_BLOCKS, 256, 0, stream>>>(xbA, row_ptr, col, deg_inv, mb);
  gemm_kernel<0><<<GEMM_BLOCKS, 1024, 0, stream>>>(mb, xbA, WT, b, xbB,
                                                   nullptr, nullptr, nullptr);
  aggregate_kernel<<<AGG_BLOCKS, 256, 0, stream>>>(xbB, row_ptr, col, deg_inv, mb);
  gemm_kernel<0><<<GEMM_BLOCKS, 1024, 0, stream>>>(mb, xbB, WT + (size_t)EMB * EMB,
                                                   b + EMB, xbA,
                                                   nullptr, nullptr, nullptr);
  aggregate_kernel<<<AGG_BLOCKS, 256, 0, stream>>>(xbA, row_ptr, col, deg_inv, mb);
  gemm_kernel<1><<<GEMM_BLOCKS, 1024, 0, stream>>>(mb, xbA, WT + (size_t)2 * EMB * EMB,
                                                   b + 2 * EMB, nullptr,
                                                   x, gamma, beta);
}

// Round 13
// 301.308 us; speedup vs baseline: 1.3846x; 1.3846x over previous
//
#include <hip/hip_runtime.h>
#include <hip/hip_bf16.h>
#include <math.h>

#define N_NODES 100000
#define EMB 128
#define N_EDGES 1600000
#define N_LAYERS 3

#define NB 400        // buckets
#define NPB 250       // nodes per bucket
#define CAP 8192      // pairs capacity per bucket (mean 4000, sigma 63)
#define CAPB 6144     // LDS stage capacity (fallback path if exceeded)
#define BSTR 16       // bcur padding stride (64B apart -> parallel L2 atomics)
#define EPT 8
#define BUCKET_THREADS 512
#define BUCKET_BLOCKS ((N_EDGES + BUCKET_THREADS * EPT - 1) / (BUCKET_THREADS * EPT))  // 391

typedef __bf16 bf16x8 __attribute__((ext_vector_type(8)));
typedef float f32x4 __attribute__((ext_vector_type(4)));

// ---------------- CSR build (unchanged: ~25us total) ----------------

__global__ __launch_bounds__(BUCKET_THREADS) void bucket_kernel(
    const int* __restrict__ src, const int* __restrict__ dst,
    int* __restrict__ bcur, unsigned* __restrict__ pairs) {
  __shared__ int scnt[NB];
  __shared__ int sbase[NB];
  const int t = threadIdx.x;
  if (t < NB) scnt[t] = 0;
  __syncthreads();
  unsigned pk[EPT];
  int bk[EPT], lofs[EPT];
  const int base_e = blockIdx.x * BUCKET_THREADS * EPT;
#pragma unroll
  for (int it = 0; it < EPT; ++it) {
    int i = base_e + it * BUCKET_THREADS + t;
    bk[it] = -1;
    if (i < N_EDGES) {
      int d = dst[i];
      int s = src[i];
      int b = d / NPB;
      int vloc = d - b * NPB;
      bk[it] = b;
      pk[it] = ((unsigned)vloc << 17) | (unsigned)s;
      lofs[it] = atomicAdd(&scnt[b], 1);
    }
  }
  __syncthreads();
  if (t < NB) sbase[t] = atomicAdd(&bcur[t * BSTR], scnt[t]);
  __syncthreads();
#pragma unroll
  for (int it = 0; it < EPT; ++it) {
    if (bk[it] >= 0) {
      int idx = sbase[bk[it]] + lofs[it];
      if (idx < CAP) pairs[(size_t)bk[it] * CAP + idx] = pk[it];
    }
  }
}

__device__ __forceinline__ int* scan512(int* pin, int* pout, int t) {
  for (int off = 1; off < 512; off <<= 1) {
    for (int i = t; i < 512; i += 256) {
      int v = pin[i];
      if (i >= off) v += pin[i - off];
      pout[i] = v;
    }
    __syncthreads();
    int* tmp = pin; pin = pout; pout = tmp;
  }
  return pin;
}

__global__ __launch_bounds__(256) void fillb_kernel(const unsigned* __restrict__ pairs,
                                                    const int* __restrict__ bcur,
                                                    int* __restrict__ row_ptr,
                                                    int* __restrict__ col) {
  __shared__ int sA[512], sB[512];
  __shared__ int cnt[NPB], cur[NPB];
  __shared__ unsigned pstage[CAPB];
  __shared__ int colstage[CAPB];
  const int t = threadIdx.x;
  const int b = blockIdx.x;

  for (int i = t; i < 512; i += 256) sA[i] = (i < NB) ? bcur[i * BSTR] : 0;
  __syncthreads();
  int* r = scan512(sA, sB, t);
  int base_b = b ? r[b - 1] : 0;
  int n = r[b] - base_b;
  if (n > CAP) n = CAP;
  const unsigned* pg = pairs + (size_t)b * CAP;
  const bool fits = (n <= CAPB);

  if (fits) for (int i = t; i < n; i += 256) pstage[i] = pg[i];
  if (t < NPB) cnt[t] = 0;
  __syncthreads();
  for (int i = t; i < n; i += 256) atomicAdd(&cnt[(fits ? pstage[i] : pg[i]) >> 17], 1);
  __syncthreads();
  for (int i = t; i < 512; i += 256) sA[i] = (i < NPB) ? cnt[i] : 0;
  __syncthreads();
  r = scan512(sA, sB, t);
  if (t < NPB) {
    int ex = r[t] - cnt[t];
    row_ptr[b * NPB + t] = base_b + ex;
    cur[t] = ex;
  }
  if (b == NB - 1 && t == 0) row_ptr[N_NODES] = N_EDGES;
  __syncthreads();
  for (int i = t; i < n; i += 256) {
    unsigned p = fits ? pstage[i] : pg[i];
    int pos = atomicAdd(&cur[p >> 17], 1);
    int s = (int)(p & 0x1FFFFu);
    if (fits) colstage[pos] = s;
    else col[base_b + pos] = s;
  }
  __syncthreads();
  if (fits) for (int i = t; i < n; i += 256) col[base_b + i] = colstage[i];
}

// ---------------- precompute ----------------

__global__ __launch_bounds__(256) void tobf16_kernel(const float* __restrict__ in,
                                                     __hip_bfloat16* __restrict__ xb) {
  size_t i = (size_t)blockIdx.x * 256 + threadIdx.x;  // 1.6M threads exactly
  const float4* p = (const float4*)in + i * 2;
  float4 a = p[0], b = p[1];
  union { __hip_bfloat16 h[8]; uint4 u; } r;
  r.h[0] = __float2bfloat16(a.x); r.h[1] = __float2bfloat16(a.y);
  r.h[2] = __float2bfloat16(a.z); r.h[3] = __float2bfloat16(a.w);
  r.h[4] = __float2bfloat16(b.x); r.h[5] = __float2bfloat16(b.y);
  r.h[6] = __float2bfloat16(b.z); r.h[7] = __float2bfloat16(b.w);
  ((uint4*)xb)[i] = r.u;
}

__global__ __launch_bounds__(256) void wt_kernel(const float* __restrict__ W,
                                                 __hip_bfloat16* __restrict__ WT) {
  int l = blockIdx.x;
  const float* Wl = W + (size_t)l * EMB * EMB;
  __hip_bfloat16* WTl = WT + (size_t)l * EMB * EMB;
  for (int i = threadIdx.x; i < EMB * EMB; i += 256) {
    int k = i >> 7, c = i & 127;
    WTl[c * EMB + k] = __float2bfloat16(Wl[i]);
  }
}

// ---------------- fused layer: aggregate + GEMM + GELU + residual (+ LN) ----

__device__ __forceinline__ float bf_lo(unsigned int w) { return __uint_as_float(w << 16); }
__device__ __forceinline__ float bf_hi(unsigned int w) { return __uint_as_float(w & 0xFFFF0000u); }

__device__ __forceinline__ float gelu_exact(float v) {
  return 0.5f * v * (1.f + erff(v * 0.70710678118654752f));
}

// Block = 512 threads (8 waves) owning 16 rows; 6250 blocks; 4 blocks/CU
// (the R10/R12 lesson: fusion wins BUT 1024-thr blocks cap at 2 blocks/CU so
// barrier-idle waves have only one other block to backfill; 512-thr gives 4
// independent blocks per CU -> gather waves from other blocks fill the gaps).
// Phase 1: 2 nodes/wave gather. Phase 2: 8 waves x one 16x16x128 MFMA tile,
// gelu staged bf16 into sM. Phase 3: coalesced row flush (2 rows/wave, amp 1)
// with bf16 residual; LAST folds LayerNorm. LDS = 4.4 KB in all variants.
template <int LAST>
__global__ __launch_bounds__(512, 8) void fused_kernel(
    const __hip_bfloat16* __restrict__ xb_in,
    const int* __restrict__ row_ptr,
    const int* __restrict__ col,
    const float* __restrict__ deg_inv,
    const __hip_bfloat16* __restrict__ WTl,
    const float* __restrict__ bias,
    __hip_bfloat16* __restrict__ xb_out,
    float* __restrict__ xf_out,
    const float* __restrict__ gamma,
    const float* __restrict__ beta) {
  __shared__ __hip_bfloat16 sM[16][136];

  const int t = threadIdx.x;
  const int w = t >> 6;         // wave 0..7
  const int lane = t & 63;
  const int q = lane >> 4;      // quarter 0..3 (edge slot / k-group)
  const int l15 = lane & 15;    // col chunk / A-row
  const int row0b = blockIdx.x * 16;

  // ---- phase 1: aggregation (wave w -> m rows w*2, w*2+1)
  const char* gbase = (const char*)xb_in + l15 * 16;  // 8 bf16 per lane
  for (int nn = 0; nn < 2; ++nn) {
    const int v = __builtin_amdgcn_readfirstlane(row0b + w * 2 + nn);
    const int beg = row_ptr[v], end = row_ptr[v + 1];
    float a0 = 0.f, a1 = 0.f, a2 = 0.f, a3 = 0.f, a4 = 0.f, a5 = 0.f, a6 = 0.f, a7 = 0.f;
#define ACC8(W) { a0 += bf_lo(W.x); a1 += bf_hi(W.x); a2 += bf_lo(W.y); a3 += bf_hi(W.y); \
                  a4 += bf_lo(W.z); a5 += bf_hi(W.z); a6 += bf_lo(W.w); a7 += bf_hi(W.w); }
    int e = beg;
    for (; e + 16 <= end; e += 16) {
      int u0 = col[e + q];
      int u1 = col[e + 4 + q];
      int u2 = col[e + 8 + q];
      int u3 = col[e + 12 + q];
      uint4 w0 = *(const uint4*)(gbase + (size_t)u0 * 256);
      uint4 w1 = *(const uint4*)(gbase + (size_t)u1 * 256);
      uint4 w2 = *(const uint4*)(gbase + (size_t)u2 * 256);
      uint4 w3 = *(const uint4*)(gbase + (size_t)u3 * 256);
      ACC8(w0) ACC8(w1) ACC8(w2) ACC8(w3)
    }
    for (; e < end; e += 4) {
      int idx = e + q;
      bool valid = idx < end;
      int u = col[valid ? idx : beg];
      uint4 w0 = *(const uint4*)(gbase + (size_t)u * 256);
      if (valid) ACC8(w0)
    }
#undef ACC8
    a0 += __shfl_xor(a0, 16, 64); a0 += __shfl_xor(a0, 32, 64);
    a1 += __shfl_xor(a1, 16, 64); a1 += __shfl_xor(a1, 32, 64);
    a2 += __shfl_xor(a2, 16, 64); a2 += __shfl_xor(a2, 32, 64);
    a3 += __shfl_xor(a3, 16, 64); a3 += __shfl_xor(a3, 32, 64);
    a4 += __shfl_xor(a4, 16, 64); a4 += __shfl_xor(a4, 32, 64);
    a5 += __shfl_xor(a5, 16, 64); a5 += __shfl_xor(a5, 32, 64);
    a6 += __shfl_xor(a6, 16, 64); a6 += __shfl_xor(a6, 32, 64);
    a7 += __shfl_xor(a7, 16, 64); a7 += __shfl_xor(a7, 32, 64);
    if (q == 0) {
      float di = deg_inv[v];
      union { __hip_bfloat16 h[8]; uint4 u4; } r;
      r.h[0] = __float2bfloat16(a0 * di); r.h[1] = __float2bfloat16(a1 * di);
      r.h[2] = __float2bfloat16(a2 * di); r.h[3] = __float2bfloat16(a3 * di);
      r.h[4] = __float2bfloat16(a4 * di); r.h[5] = __float2bfloat16(a5 * di);
      r.h[6] = __float2bfloat16(a6 * di); r.h[7] = __float2bfloat16(a7 * di);
      *(uint4*)(&sM[w * 2 + nn][l15 * 8]) = r.u4;
    }
  }

  // ---- B fragments (independent of sM; issued before barrier; L2-hot)
  bf16x8 bfr[4];
  {
    const __hip_bfloat16* wp = WTl + (size_t)(w * 16 + l15) * EMB + q * 8;
#pragma unroll
    for (int ks = 0; ks < 4; ++ks)
      bfr[ks] = *(const bf16x8*)(wp + ks * 32);
  }
  __syncthreads();

  // ---- phase 2: MFMA (all 8 waves, wave w -> col tile w of all 16 rows)
  f32x4 acc = (f32x4)(0.f);
#pragma unroll
  for (int ks = 0; ks < 4; ++ks) {
    bf16x8 af = *(const bf16x8*)(&sM[l15][q * 8 + ks * 32]);
    acc = __builtin_amdgcn_mfma_f32_16x16x32_bf16(af, bfr[ks], acc, 0, 0, 0);
  }
  __syncthreads();  // all sM reads done before overwrite
  {
    const int colg = w * 16 + l15;
    const float bb = bias[colg];
#pragma unroll
    for (int j = 0; j < 4; ++j)
      sM[q * 4 + j][colg] = __float2bfloat16(gelu_exact(acc[j] + bb));
  }
  __syncthreads();

  // ---- phase 3: coalesced row flush, wave w -> rows 2w, 2w+1
#pragma unroll
  for (int rr = 0; rr < 2; ++rr) {
    const int r = w * 2 + rr;
    const size_t rowoff = (size_t)(row0b + r) * EMB;
    unsigned rg = *(const unsigned*)(&sM[r][lane * 2]);            // gelu pair
    unsigned rd = *(const unsigned*)((const char*)xb_in + (rowoff + lane * 2) * 2);
    float v1 = bf_lo(rd) + bf_lo(rg);
    float v2 = bf_hi(rd) + bf_hi(rg);
    if (!LAST) {
      union { __hip_bfloat16 h[2]; unsigned u; } o;
      o.h[0] = __float2bfloat16(v1);
      o.h[1] = __float2bfloat16(v2);
      *(unsigned*)((char*)xb_out + (rowoff + lane * 2) * 2) = o.u;
    } else {
      float s = v1 + v2;
      float sq = fmaf(v1, v1, v2 * v2);
      for (int off = 1; off < 64; off <<= 1) {
        s += __shfl_xor(s, off, 64);
        sq += __shfl_xor(sq, off, 64);
      }
      float mu = s * (1.f / EMB);
      float var = sq * (1.f / EMB) - mu * mu;
      float rstd = rsqrtf(var + 1e-5f);
      float2 g = *(const float2*)(gamma + lane * 2);
      float2 be = *(const float2*)(beta + lane * 2);
      float2 o;
      o.x = (v1 - mu) * rstd * g.x + be.x;
      o.y = (v2 - mu) * rstd * g.y + be.y;
      *(float2*)(xf_out + rowoff + lane * 2) = o;
    }
  }
}

// ---------------- launch ----------------

extern "C" void kernel_launch(void* const* d_in, const int* in_sizes, int n_in,
                              void* d_out, int out_size, void* d_ws, size_t ws_size,
                              hipStream_t stream) {
  const int* edge_index = (const int*)d_in[0];
  const float* deg_inv = (const float*)d_in[1];
  const float* node_emb = (const float*)d_in[2];
  const float* W = (const float*)d_in[3];
  const float* b = (const float*)d_in[4];
  const float* gamma = (const float*)d_in[5];
  const float* beta = (const float*)d_in[6];
  const int* src = edge_index;
  const int* dst = edge_index + N_EDGES;
  float* x = (float*)d_out;  // fp32 output written once, post-LN

  char* ws = (char*)d_ws;
  auto take = [&](size_t bytes) {
    char* p = ws;
    ws += (bytes + 255) & ~(size_t)255;
    return p;
  };
  __hip_bfloat16* xbA = (__hip_bfloat16*)take((size_t)N_NODES * EMB * 2);  // bf16 stream ping
  __hip_bfloat16* xbB = (__hip_bfloat16*)take((size_t)N_NODES * EMB * 2);  // bf16 stream pong
  __hip_bfloat16* WT = (__hip_bfloat16*)take((size_t)N_LAYERS * EMB * EMB * 2);
  int* row_ptr = (int*)take((N_NODES + 1) * sizeof(int));
  int* col = (int*)take(N_EDGES * sizeof(int));
  int* bcur = (int*)take(NB * BSTR * sizeof(int));
  unsigned* pairs = (unsigned*)xbB;  // alias: consumed by fillb before layer 0 writes xbB

  hipMemsetAsync(bcur, 0, NB * BSTR * sizeof(int), stream);

  tobf16_kernel<<<N_NODES * EMB / 8 / 256, 256, 0, stream>>>(node_emb, xbA);
  wt_kernel<<<N_LAYERS, 256, 0, stream>>>(W, WT);

  bucket_kernel<<<BUCKET_BLOCKS, BUCKET_THREADS, 0, stream>>>(src, dst, bcur, pairs);
  fillb_kernel<<<NB, 256, 0, stream>>>(pairs, bcur, row_ptr, col);

  const int NBLK = N_NODES / 16;  // 6250, exact
  fused_kernel<0><<<NBLK, 512, 0, stream>>>(xbA, row_ptr, col, deg_inv,
                                            WT, b, xbB, nullptr, nullptr, nullptr);
  fused_kernel<0><<<NBLK, 512, 0, stream>>>(xbB, row_ptr, col, deg_inv,
                                            WT + (size_t)EMB * EMB, b + EMB,
                                            xbA, nullptr, nullptr, nullptr);
  fused_kernel<1><<<NBLK, 512, 0, stream>>>(xbA, row_ptr, col, deg_inv,
                                            WT + (size_t)2 * EMB * EMB, b + 2 * EMB,
                                            nullptr, x, gamma, beta);
}

// Round 14
// 292.864 us; speedup vs baseline: 1.4245x; 1.0288x over previous
//
#include <hip/hip_runtime.h>
#include <hip/hip_bf16.h>
#include <math.h>

#define N_NODES 100000
#define EMB 128
#define N_EDGES 1600000
#define N_LAYERS 3

#define NB 400        // buckets
#define NPB 250       // nodes per bucket
#define CAP 8192      // pairs capacity per bucket (mean 4000, sigma 63)
#define CAPB 6144     // LDS stage capacity (fallback path if exceeded)
#define BSTR 16       // bcur padding stride (64B apart -> parallel L2 atomics)
#define EPT 8
#define BUCKET_THREADS 512
#define BUCKET_BLOCKS ((N_EDGES + BUCKET_THREADS * EPT - 1) / (BUCKET_THREADS * EPT))  // 391

typedef __bf16 bf16x8 __attribute__((ext_vector_type(8)));
typedef float f32x4 __attribute__((ext_vector_type(4)));

// ---------------- CSR build (unchanged: ~25us total) ----------------

__global__ __launch_bounds__(BUCKET_THREADS) void bucket_kernel(
    const int* __restrict__ src, const int* __restrict__ dst,
    int* __restrict__ bcur, unsigned* __restrict__ pairs) {
  __shared__ int scnt[NB];
  __shared__ int sbase[NB];
  const int t = threadIdx.x;
  if (t < NB) scnt[t] = 0;
  __syncthreads();
  unsigned pk[EPT];
  int bk[EPT], lofs[EPT];
  const int base_e = blockIdx.x * BUCKET_THREADS * EPT;
#pragma unroll
  for (int it = 0; it < EPT; ++it) {
    int i = base_e + it * BUCKET_THREADS + t;
    bk[it] = -1;
    if (i < N_EDGES) {
      int d = dst[i];
      int s = src[i];
      int b = d / NPB;
      int vloc = d - b * NPB;
      bk[it] = b;
      pk[it] = ((unsigned)vloc << 17) | (unsigned)s;
      lofs[it] = atomicAdd(&scnt[b], 1);
    }
  }
  __syncthreads();
  if (t < NB) sbase[t] = atomicAdd(&bcur[t * BSTR], scnt[t]);
  __syncthreads();
#pragma unroll
  for (int it = 0; it < EPT; ++it) {
    if (bk[it] >= 0) {
      int idx = sbase[bk[it]] + lofs[it];
      if (idx < CAP) pairs[(size_t)bk[it] * CAP + idx] = pk[it];
    }
  }
}

__device__ __forceinline__ int* scan512(int* pin, int* pout, int t) {
  for (int off = 1; off < 512; off <<= 1) {
    for (int i = t; i < 512; i += 256) {
      int v = pin[i];
      if (i >= off) v += pin[i - off];
      pout[i] = v;
    }
    __syncthreads();
    int* tmp = pin; pin = pout; pout = tmp;
  }
  return pin;
}

__global__ __launch_bounds__(256) void fillb_kernel(const unsigned* __restrict__ pairs,
                                                    const int* __restrict__ bcur,
                                                    int* __restrict__ row_ptr,
                                                    int* __restrict__ col) {
  __shared__ int sA[512], sB[512];
  __shared__ int cnt[NPB], cur[NPB];
  __shared__ unsigned pstage[CAPB];
  __shared__ int colstage[CAPB];
  const int t = threadIdx.x;
  const int b = blockIdx.x;

  for (int i = t; i < 512; i += 256) sA[i] = (i < NB) ? bcur[i * BSTR] : 0;
  __syncthreads();
  int* r = scan512(sA, sB, t);
  int base_b = b ? r[b - 1] : 0;
  int n = r[b] - base_b;
  if (n > CAP) n = CAP;
  const unsigned* pg = pairs + (size_t)b * CAP;
  const bool fits = (n <= CAPB);

  if (fits) for (int i = t; i < n; i += 256) pstage[i] = pg[i];
  if (t < NPB) cnt[t] = 0;
  __syncthreads();
  for (int i = t; i < n; i += 256) atomicAdd(&cnt[(fits ? pstage[i] : pg[i]) >> 17], 1);
  __syncthreads();
  for (int i = t; i < 512; i += 256) sA[i] = (i < NPB) ? cnt[i] : 0;
  __syncthreads();
  r = scan512(sA, sB, t);
  if (t < NPB) {
    int ex = r[t] - cnt[t];
    row_ptr[b * NPB + t] = base_b + ex;
    cur[t] = ex;
  }
  if (b == NB - 1 && t == 0) row_ptr[N_NODES] = N_EDGES;
  __syncthreads();
  for (int i = t; i < n; i += 256) {
    unsigned p = fits ? pstage[i] : pg[i];
    int pos = atomicAdd(&cur[p >> 17], 1);
    int s = (int)(p & 0x1FFFFu);
    if (fits) colstage[pos] = s;
    else col[base_b + pos] = s;
  }
  __syncthreads();
  if (fits) for (int i = t; i < n; i += 256) col[base_b + i] = colstage[i];
}

// ---------------- precompute: xb=bf16(node_emb) + WT transpose, one launch ----

__global__ __launch_bounds__(256) void prep_kernel(const float* __restrict__ in,
                                                   __hip_bfloat16* __restrict__ xb,
                                                   const float* __restrict__ W,
                                                   __hip_bfloat16* __restrict__ WT) {
  if (blockIdx.x < N_NODES * EMB / 8 / 256) {
    size_t i = (size_t)blockIdx.x * 256 + threadIdx.x;
    const float4* p = (const float4*)in + i * 2;
    float4 a = p[0], b = p[1];
    union { __hip_bfloat16 h[8]; uint4 u; } r;
    r.h[0] = __float2bfloat16(a.x); r.h[1] = __float2bfloat16(a.y);
    r.h[2] = __float2bfloat16(a.z); r.h[3] = __float2bfloat16(a.w);
    r.h[4] = __float2bfloat16(b.x); r.h[5] = __float2bfloat16(b.y);
    r.h[6] = __float2bfloat16(b.z); r.h[7] = __float2bfloat16(b.w);
    ((uint4*)xb)[i] = r.u;
  } else {
    int l = blockIdx.x - N_NODES * EMB / 8 / 256;  // 0..2
    const float* Wl = W + (size_t)l * EMB * EMB;
    __hip_bfloat16* WTl = WT + (size_t)l * EMB * EMB;
    for (int i = threadIdx.x; i < EMB * EMB; i += 256) {
      int k = i >> 7, c = i & 127;
      WTl[c * EMB + k] = __float2bfloat16(Wl[i]);
    }
  }
}

// ---------------- fused layer: aggregate + GEMM + GELU + residual (+ LN) ----

__device__ __forceinline__ float bf_lo(unsigned int w) { return __uint_as_float(w << 16); }
__device__ __forceinline__ float bf_hi(unsigned int w) { return __uint_as_float(w & 0xFFFF0000u); }

__device__ __forceinline__ float gelu_exact(float v) {
  return 0.5f * v * (1.f + erff(v * 0.70710678118654752f));
}

// Block = 512 threads (8 waves) / 16 rows; 6250 blocks; 4 blocks/CU.
// Phase 1 gather = R7-style dword: lane owns cols 2l,2l+1 of the node's m-row;
// one 256B row per load instruction (64 x 4B coalesced), 4-edge unroll (4 rows
// in flight), 2 fadds/edge, ZERO cross-lane shuffles (R13's quarter-wave uint4
// paid 16 DS-pipe shuffle ops per node ~ 50% DS-pipe busy). One pack + 4B LDS
// write per node. Phase 2: 8 waves x one 16x16x128 MFMA, gelu -> sG (separate
// buffer: no middle barrier). Phase 3: coalesced row flush; resid rows
// pre-loaded to regs before barrier 1. LAST folds LayerNorm.
template <int LAST>
__global__ __launch_bounds__(512, 8) void fused_kernel(
    const __hip_bfloat16* __restrict__ xb_in,
    const int* __restrict__ row_ptr,
    const int* __restrict__ col,
    const float* __restrict__ deg_inv,
    const __hip_bfloat16* __restrict__ WTl,
    const float* __restrict__ bias,
    __hip_bfloat16* __restrict__ xb_out,
    float* __restrict__ xf_out,
    const float* __restrict__ gamma,
    const float* __restrict__ beta) {
  __shared__ __hip_bfloat16 sM[16][136];   // aggregate m tile
  __shared__ __hip_bfloat16 sG[16][136];   // gelu output tile

  const int t = threadIdx.x;
  const int w = t >> 6;         // wave 0..7
  const int lane = t & 63;
  const int q = lane >> 4;      // k-group (MFMA)
  const int l15 = lane & 15;    // A-row (MFMA)
  const int row0b = blockIdx.x * 16;

  // ---- phase 1: gather, 2 nodes per wave, lane = col pair 2l,2l+1
  const char* gbase = (const char*)xb_in + lane * 4;
  for (int nn = 0; nn < 2; ++nn) {
    const int v = __builtin_amdgcn_readfirstlane(row0b + w * 2 + nn);
    const int beg = row_ptr[v], end = row_ptr[v + 1];
    float ax = 0.f, ay = 0.f;
    int e = beg;
    for (; e + 4 <= end; e += 4) {
      int u0 = col[e], u1 = col[e + 1], u2 = col[e + 2], u3 = col[e + 3];
      unsigned w0 = *(const unsigned*)(gbase + (size_t)u0 * 256);
      unsigned w1 = *(const unsigned*)(gbase + (size_t)u1 * 256);
      unsigned w2 = *(const unsigned*)(gbase + (size_t)u2 * 256);
      unsigned w3 = *(const unsigned*)(gbase + (size_t)u3 * 256);
      ax += bf_lo(w0) + bf_lo(w1) + bf_lo(w2) + bf_lo(w3);
      ay += bf_hi(w0) + bf_hi(w1) + bf_hi(w2) + bf_hi(w3);
    }
    for (; e < end; ++e) {
      unsigned w0 = *(const unsigned*)(gbase + (size_t)col[e] * 256);
      ax += bf_lo(w0);
      ay += bf_hi(w0);
    }
    float di = deg_inv[v];
    union { __hip_bfloat16 h[2]; unsigned u; } r;
    r.h[0] = __float2bfloat16(ax * di);
    r.h[1] = __float2bfloat16(ay * di);
    *(unsigned*)(&sM[w * 2 + nn][lane * 2]) = r.u;
  }

  // ---- B fragments + early residual loads (independent of sM; pre-barrier)
  bf16x8 bfr[4];
  {
    const __hip_bfloat16* wp = WTl + (size_t)(w * 16 + l15) * EMB + q * 8;
#pragma unroll
    for (int ks = 0; ks < 4; ++ks)
      bfr[ks] = *(const bf16x8*)(wp + ks * 32);
  }
  unsigned rd0 = *(const unsigned*)((const char*)xb_in +
                                    ((size_t)(row0b + w * 2) * EMB + lane * 2) * 2);
  unsigned rd1 = *(const unsigned*)((const char*)xb_in +
                                    ((size_t)(row0b + w * 2 + 1) * EMB + lane * 2) * 2);
  __syncthreads();

  // ---- phase 2: MFMA (wave w -> col tile w of all 16 rows), gelu -> sG
  f32x4 acc = (f32x4)(0.f);
#pragma unroll
  for (int ks = 0; ks < 4; ++ks) {
    bf16x8 af = *(const bf16x8*)(&sM[l15][q * 8 + ks * 32]);
    acc = __builtin_amdgcn_mfma_f32_16x16x32_bf16(af, bfr[ks], acc, 0, 0, 0);
  }
  {
    const int colg = w * 16 + l15;
    const float bb = bias[colg];
#pragma unroll
    for (int j = 0; j < 4; ++j)
      sG[q * 4 + j][colg] = __float2bfloat16(gelu_exact(acc[j] + bb));
  }
  __syncthreads();

  // ---- phase 3: coalesced row flush, wave w -> rows 2w, 2w+1
#pragma unroll
  for (int rr = 0; rr < 2; ++rr) {
    const int r = w * 2 + rr;
    const size_t rowoff = (size_t)(row0b + r) * EMB;
    unsigned rg = *(const unsigned*)(&sG[r][lane * 2]);
    unsigned rd = rr ? rd1 : rd0;
    float v1 = bf_lo(rd) + bf_lo(rg);
    float v2 = bf_hi(rd) + bf_hi(rg);
    if (!LAST) {
      union { __hip_bfloat16 h[2]; unsigned u; } o;
      o.h[0] = __float2bfloat16(v1);
      o.h[1] = __float2bfloat16(v2);
      *(unsigned*)((char*)xb_out + (rowoff + lane * 2) * 2) = o.u;
    } else {
      float s = v1 + v2;
      float sq = fmaf(v1, v1, v2 * v2);
      for (int off = 1; off < 64; off <<= 1) {
        s += __shfl_xor(s, off, 64);
        sq += __shfl_xor(sq, off, 64);
      }
      float mu = s * (1.f / EMB);
      float var = sq * (1.f / EMB) - mu * mu;
      float rstd = rsqrtf(var + 1e-5f);
      float2 g = *(const float2*)(gamma + lane * 2);
      float2 be = *(const float2*)(beta + lane * 2);
      float2 o;
      o.x = (v1 - mu) * rstd * g.x + be.x;
      o.y = (v2 - mu) * rstd * g.y + be.y;
      *(float2*)(xf_out + rowoff + lane * 2) = o;
    }
  }
}

// ---------------- launch ----------------

extern "C" void kernel_launch(void* const* d_in, const int* in_sizes, int n_in,
                              void* d_out, int out_size, void* d_ws, size_t ws_size,
                              hipStream_t stream) {
  const int* edge_index = (const int*)d_in[0];
  const float* deg_inv = (const float*)d_in[1];
  const float* node_emb = (const float*)d_in[2];
  const float* W = (const float*)d_in[3];
  const float* b = (const float*)d_in[4];
  const float* gamma = (const float*)d_in[5];
  const float* beta = (const float*)d_in[6];
  const int* src = edge_index;
  const int* dst = edge_index + N_EDGES;
  float* x = (float*)d_out;  // fp32 output written once, post-LN

  char* ws = (char*)d_ws;
  auto take = [&](size_t bytes) {
    char* p = ws;
    ws += (bytes + 255) & ~(size_t)255;
    return p;
  };
  __hip_bfloat16* xbA = (__hip_bfloat16*)take((size_t)N_NODES * EMB * 2);  // bf16 stream ping
  __hip_bfloat16* xbB = (__hip_bfloat16*)take((size_t)N_NODES * EMB * 2);  // bf16 stream pong
  __hip_bfloat16* WT = (__hip_bfloat16*)take((size_t)N_LAYERS * EMB * EMB * 2);
  int* row_ptr = (int*)take((N_NODES + 1) * sizeof(int));
  int* col = (int*)take(N_EDGES * sizeof(int));
  int* bcur = (int*)take(NB * BSTR * sizeof(int));
  unsigned* pairs = (unsigned*)xbB;  // alias: consumed by fillb before layer 0 writes xbB

  hipMemsetAsync(bcur, 0, NB * BSTR * sizeof(int), stream);

  prep_kernel<<<N_NODES * EMB / 8 / 256 + N_LAYERS, 256, 0, stream>>>(node_emb, xbA, W, WT);

  bucket_kernel<<<BUCKET_BLOCKS, BUCKET_THREADS, 0, stream>>>(src, dst, bcur, pairs);
  fillb_kernel<<<NB, 256, 0, stream>>>(pairs, bcur, row_ptr, col);

  const int NBLK = N_NODES / 16;  // 6250, exact
  fused_kernel<0><<<NBLK, 512, 0, stream>>>(xbA, row_ptr, col, deg_inv,
                                            WT, b, xbB, nullptr, nullptr, nullptr);
  fused_kernel<0><<<NBLK, 512, 0, stream>>>(xbB, row_ptr, col, deg_inv,
                                            WT + (size_t)EMB * EMB, b + EMB,
                                            xbA, nullptr, nullptr, nullptr);
  fused_kernel<1><<<NBLK, 512, 0, stream>>>(xbA, row_ptr, col, deg_inv,
                                            WT + (size_t)2 * EMB * EMB, b + 2 * EMB,
                                            nullptr, x, gamma, beta);
}